// Round 9
// baseline (58.303 us; speedup 1.0000x reference)
//
#include <hip/hip_runtime.h>
#include <hip/hip_bf16.h>

#define HW 16384
#define W_IMG 128
#define BM_TOT 5
#define PRE 0.5101179482f   // (1/sqrt(8)) * log2(e): folded into Q so p = exp2(s)

typedef __attribute__((ext_vector_type(8))) short bf16x8;
typedef __attribute__((ext_vector_type(4))) float f32x4;

__device__ __forceinline__ short f2b(float f) {
    __hip_bfloat16 h = __float2bfloat16(f);
    union { __hip_bfloat16 h; short s; } c; c.h = h; return c.s;
}
__device__ __forceinline__ float b2f(short s) {
    union { unsigned u; float f; } v; v.u = ((unsigned)(unsigned short)s) << 16;
    return v.f;
}
__device__ __forceinline__ unsigned pk2(float a, float b) {   // -> v_cvt_pk_bf16_f32
    __hip_bfloat162 h = __float22bfloat162_rn(make_float2(a, b));
    union { __hip_bfloat162 h; unsigned u; } c; c.h = h; return c.u;
}
__device__ __forceinline__ float fexp2(float x) {             // ONE v_exp_f32, no libcall
#if __has_builtin(__builtin_amdgcn_exp2f)
    return __builtin_amdgcn_exp2f(x);
#else
    float r; asm("v_exp_f32 %0, %1" : "=v"(r) : "v"(x)); return r;
#endif
}

// ---------------------------------------------------------------------------
// k_prep (1 block): weight tables.
// ---------------------------------------------------------------------------
__global__ __launch_bounds__(256) void k_prep(
    const float* __restrict__ w_qkv, const float* __restrict__ w_high,
    const float* __restrict__ b_high, const float* __restrict__ gamma,
    const float* __restrict__ beta, const float* __restrict__ w_out,
    const float* __restrict__ w_rgb,
    short* __restrict__ wqkvb, float* __restrict__ CW,
    short* __restrict__ wcombb)
{
    const int tid = threadIdx.x;
    for (int i = tid; i < 6144; i += 256)
        ((unsigned*)wqkvb)[i] = pk2(w_qkv[2 * i], w_qkv[2 * i + 1]);
    if (tid < 64) {
        float4 a = {w_high[tid * 3], w_high[tid * 3 + 1], w_high[tid * 3 + 2], b_high[tid]};
        float4 b = {gamma[tid], beta[tid], 0.f, 0.f};
        *(float4*)&CW[tid * 8] = a;
        *(float4*)&CW[tid * 8 + 4] = b;
    }
    for (int i = tid; i < 1024; i += 256) {
        short wc = 0;
        if (i < 192) {
            int c = i >> 6, e = i & 63;
            float a = 0.f;
            for (int e2 = 0; e2 < 64; ++e2)
                a = fmaf(w_rgb[c * 64 + e2], w_out[e2 * 64 + e], a);
            wc = f2b(a);
        }
        wcombb[i] = wc;
    }
}

// ---------------------------------------------------------------------------
// Kernel 1: conv+LN (4 threads/pixel, quad-shfl stats) + featRGB projection
// + MFMA 64x192 QKV projection.
// ---------------------------------------------------------------------------
__global__ __launch_bounds__(256) void k_qkv(
    const float* __restrict__ x, const short* __restrict__ wqkvb,
    const float* __restrict__ CW, const float* __restrict__ pos_q,
    const float* __restrict__ w_rgb,
    float* __restrict__ featrgb, short* __restrict__ qmid,
    short* __restrict__ kbuf, short* __restrict__ vbuf)
{
    __shared__ short XS[64 * 72];
    __shared__ short TLk[64 * 72];
    __shared__ short TLv[64 * 72];
    __shared__ short TLq[64 * 72];
    __shared__ float WL[64 * 8];
    __shared__ float WRL[192];

    const int tid = threadIdx.x, blk = blockIdx.x;
    const int bm = blk >> 8, p0 = (blk & 255) * 64;
    const int pixbase = blk * 64;
    const int wv = tid >> 6, lane = tid & 63;
    const int col = lane & 15, grp = lane >> 4;

    if (tid < 128) ((float4*)WL)[tid] = ((const float4*)CW)[tid];
    else if (tid < 176) ((float4*)WRL)[tid - 128] = ((const float4*)w_rgb)[tid - 128];
    __syncthreads();

    // ---- conv + LN + rgb-residual: 4 threads/pixel, 16 channels each ----
    {
        const int px_l = tid >> 2, part = tid & 3;
        const int p = p0 + px_l;
        const float* xp = x + (size_t)bm * 3 * HW + p;
        const float x0 = xp[0], x1 = xp[HW], x2 = xp[2 * HW];
        float f[16]; float s = 0.f, s2 = 0.f;
        #pragma unroll
        for (int j = 0; j < 16; ++j) {
            const int ch = part * 16 + j;
            float4 wa = *(const float4*)&WL[ch * 8];
            f[j] = fmaf(wa.x, x0, fmaf(wa.y, x1, fmaf(wa.z, x2, wa.w)));
            s += f[j]; s2 = fmaf(f[j], f[j], s2);
        }
        float r0 = 0.f, r1 = 0.f, r2 = 0.f;
        #pragma unroll
        for (int j = 0; j < 16; ++j) {
            const float fj = f[j];
            r0 = fmaf(fj, WRL[part * 16 + j], r0);
            r1 = fmaf(fj, WRL[64 + part * 16 + j], r1);
            r2 = fmaf(fj, WRL[128 + part * 16 + j], r2);
        }
        s  += __shfl_xor(s, 1);  s  += __shfl_xor(s, 2);
        s2 += __shfl_xor(s2, 1); s2 += __shfl_xor(s2, 2);
        r0 += __shfl_xor(r0, 1); r0 += __shfl_xor(r0, 2);
        r1 += __shfl_xor(r1, 1); r1 += __shfl_xor(r1, 2);
        r2 += __shfl_xor(r2, 1); r2 += __shfl_xor(r2, 2);
        if (part < 3) {
            float rv = part == 0 ? r0 : (part == 1 ? r1 : r2);
            featrgb[((size_t)bm * 3 + part) * HW + p] = rv;
        }
        const float mu = s * 0.015625f;
        const float var = s2 * 0.015625f - mu * mu;
        const float rs = rsqrtf(var + 1e-6f);
        unsigned xw[8];
        #pragma unroll
        for (int j2 = 0; j2 < 8; ++j2) {
            const int ch = part * 16 + 2 * j2;
            float4 g0 = *(const float4*)&WL[ch * 8 + 4];
            float4 g1 = *(const float4*)&WL[ch * 8 + 12];
            xw[j2] = pk2((f[2 * j2] - mu) * rs * g0.x + g0.y,
                         (f[2 * j2 + 1] - mu) * rs * g1.x + g1.y);
        }
        *(uint4*)&XS[px_l * 72 + part * 16]     = make_uint4(xw[0], xw[1], xw[2], xw[3]);
        *(uint4*)&XS[px_l * 72 + part * 16 + 8] = make_uint4(xw[4], xw[5], xw[6], xw[7]);
    }

    // ---- B-fragments from pre-packed bf16 w_qkv ----
    bf16x8 Bf[3][2];
    #pragma unroll
    for (int jj = 0; jj < 3; ++jj) {
        int jt = wv + jj * 4;
        #pragma unroll
        for (int kc = 0; kc < 2; ++kc)
            Bf[jj][kc] = *(const bf16x8*)&wqkvb[(jt * 16 + col) * 64 + kc * 32 + grp * 8];
    }
    __syncthreads();

    // ---- MFMA projection into TL buffers ----
    #pragma unroll
    for (int pt = 0; pt < 4; ++pt) {
        bf16x8 A0 = *(const bf16x8*)&XS[(pt * 16 + col) * 72 + grp * 8];
        bf16x8 A1 = *(const bf16x8*)&XS[(pt * 16 + col) * 72 + 32 + grp * 8];

        f32x4 aK = {0.f, 0.f, 0.f, 0.f};
        aK = __builtin_amdgcn_mfma_f32_16x16x32_bf16(Bf[1][0], A0, aK, 0, 0, 0);
        aK = __builtin_amdgcn_mfma_f32_16x16x32_bf16(Bf[1][1], A1, aK, 0, 0, 0);
        uint2 kw = {pk2(aK[0], aK[1]), pk2(aK[2], aK[3])};
        *(uint2*)&TLk[(pt * 16 + col) * 72 + wv * 16 + grp * 4] = kw;

        f32x4 aV = {0.f, 0.f, 0.f, 0.f};
        aV = __builtin_amdgcn_mfma_f32_16x16x32_bf16(A0, Bf[2][0], aV, 0, 0, 0);
        aV = __builtin_amdgcn_mfma_f32_16x16x32_bf16(A1, Bf[2][1], aV, 0, 0, 0);
        #pragma unroll
        for (int i = 0; i < 4; ++i)
            TLv[(pt * 16 + grp * 4 + i) * 72 + wv * 16 + col] = f2b(aV[i]);

        if (bm == 2) {
            f32x4 aQ = {0.f, 0.f, 0.f, 0.f};
            aQ = __builtin_amdgcn_mfma_f32_16x16x32_bf16(Bf[0][0], A0, aQ, 0, 0, 0);
            aQ = __builtin_amdgcn_mfma_f32_16x16x32_bf16(Bf[0][1], A1, aQ, 0, 0, 0);
            int p = p0 + pt * 16 + col;
            int qq = ((p >> 7) & 7) * 8 + (p & 7);
            float4 pq = *(const float4*)&pos_q[qq * 64 + wv * 16 + grp * 4];
            uint2 qw = {pk2((aQ[0] + pq.x) * PRE, (aQ[1] + pq.y) * PRE),
                        pk2((aQ[2] + pq.z) * PRE, (aQ[3] + pq.w) * PRE)};
            *(uint2*)&TLq[(pt * 16 + col) * 72 + wv * 16 + grp * 4] = qw;
        }
    }
    __syncthreads();

    // ---- coalesced copy-out ----
    #pragma unroll
    for (int it = 0; it < 2; ++it) {
        int j = it * 256 + tid;
        int row = j >> 3, seg = j & 7;
        *(uint4*)&kbuf[((size_t)pixbase + row) * 64 + seg * 8] =
            *(const uint4*)&TLk[row * 72 + seg * 8];
        *(uint4*)&vbuf[((size_t)pixbase + row) * 64 + seg * 8] =
            *(const uint4*)&TLv[row * 72 + seg * 8];
        if (bm == 2)
            *(uint4*)&qmid[((size_t)p0 + row) * 64 + seg * 8] =
                *(const uint4*)&TLq[row * 72 + seg * 8];
    }
}

// ---------------------------------------------------------------------------
// Kernel 2: windowed attention + fused epilogue. 512 threads, wave = head.
// K- and V-fragments hoisted to registers ONCE per wave (loop-invariant
// across the 4 q-tiles) -> 42 fewer ds_read_b128 per wave (LDS pipe is the
// bottleneck). Score->exp->pack fused per tile to keep sc dead (VGPR fit).
// ---------------------------------------------------------------------------
__global__ __launch_bounds__(512, 4) void k_attn(
    const short* __restrict__ qmid, const short* __restrict__ kbuf,
    const short* __restrict__ vbuf,
    const float* __restrict__ pos_k, const float* __restrict__ b_rgb,
    const float* __restrict__ featrgb, const short* __restrict__ wcombb,
    float* __restrict__ outp)
{
    __shared__ char smem[48448];
    short* Klds = (short*)smem;                  // [144][72] bf16, K + pos_k
    short* Vt   = (short*)(smem + 20736);        // [64][152] bf16 + slack
    short* OL   = (short*)smem;                  // overlay after attention
    // P slot buffers: smem + 40224, 1 KB per wave (8 waves)

    const int tid = threadIdx.x, blk = blockIdx.x;
    const int bm = blk >> 8, widx = blk & 255;
    const int wi = widx >> 4, wj = widx & 15;
    const int head = tid >> 6, lane = tid & 63;
    const int col = lane & 15, grp = lane >> 4;

    // ---- stage K(+pos_k): key-fast -> coalesced reads ----
    for (int idx = tid; idx < 1152; idx += 512) {
        int kk = idx >> 3, chunk = idx & 7;
        int r = kk / 12, c = kk - r * 12;
        int hh = wi * 8 - 2 + r, ww = wj * 8 - 2 + c;
        uint4 kraw = {0, 0, 0, 0};
        if ((unsigned)hh < 128u && (unsigned)ww < 128u)
            kraw = *(const uint4*)&kbuf[((size_t)bm * HW + hh * W_IMG + ww) * 64 + chunk * 8];
        const float* pk = &pos_k[kk * 64 + chunk * 8];
        float4 pk0 = *(const float4*)pk;
        float4 pk1 = *(const float4*)(pk + 4);
        union { uint4 q; short s[8]; } ku; ku.q = kraw;
        uint4 ko;
        ko.x = pk2(b2f(ku.s[0]) + pk0.x, b2f(ku.s[1]) + pk0.y);
        ko.y = pk2(b2f(ku.s[2]) + pk0.z, b2f(ku.s[3]) + pk0.w);
        ko.z = pk2(b2f(ku.s[4]) + pk1.x, b2f(ku.s[5]) + pk1.y);
        ko.w = pk2(b2f(ku.s[6]) + pk1.z, b2f(ku.s[7]) + pk1.w);
        *(uint4*)&Klds[kk * 72 + chunk * 8] = ko;
    }

    // ---- stage V^T: chunk-major ----
    for (int idx = tid; idx < 1152; idx += 512) {
        int chunk = idx / 144, kk = idx - chunk * 144;
        int r = kk / 12, c = kk - r * 12;
        int hh = wi * 8 - 2 + r, ww = wj * 8 - 2 + c;
        uint4 vraw = {0, 0, 0, 0};
        if ((unsigned)hh < 128u && (unsigned)ww < 128u)
            vraw = *(const uint4*)&vbuf[((size_t)bm * HW + hh * W_IMG + ww) * 64 + chunk * 8];
        union { uint4 q; short s[8]; } vu; vu.q = vraw;
        #pragma unroll
        for (int cc = 0; cc < 8; ++cc)
            Vt[(chunk * 8 + cc) * 152 + kk] = vu.s[cc];
    }
    if (tid < 64) *(uint4*)&Vt[tid * 152 + 144] = (uint4){0, 0, 0, 0};
    if (tid < 2)  *(uint4*)&Vt[64 * 152 + tid * 8] = (uint4){0, 0, 0, 0};

    // ---- Q fragments (pos_q & scale pre-folded) ----
    uint4 qraw[4] = {{0,0,0,0},{0,0,0,0},{0,0,0,0},{0,0,0,0}};
    if (grp == 0) {
        #pragma unroll
        for (int qt = 0; qt < 4; ++qt) {
            int q = qt * 16 + col;
            int pix = (wi * 8 + (q >> 3)) * W_IMG + wj * 8 + (q & 7);
            qraw[qt] = *(const uint4*)&qmid[(size_t)pix * 64 + head * 8];
        }
    }
    __syncthreads();

    // ---- hoist K- and V-fragments into registers (invariant over qt) ----
    bf16x8 kfr[9];
    #pragma unroll
    for (int kt = 0; kt < 9; ++kt)
        kfr[kt] = *(const bf16x8*)&Klds[(kt * 16 + col) * 72 + head * 8];
    bf16x8 vfr[5];
    #pragma unroll
    for (int kt2 = 0; kt2 < 5; ++kt2)
        vfr[kt2] = *(const bf16x8*)&Vt[(head * 8 + (lane & 7)) * 152 + kt2 * 32 + grp * 8];

    unsigned* PBh = (unsigned*)(smem + 40224 + head * 1024);
    const int slot_w = (grp * 16 + (col ^ grp)) * 4;
    const int g0 = 2 * (grp & 1);
    const int slotr1 = (g0 * 16 + (col ^ g0)) * 4 + (grp >> 1) * 2;
    const int slotr2 = ((g0 + 1) * 16 + (col ^ (g0 + 1))) * 4 + (grp >> 1) * 2;

    f32x4 oacc[4];
    float linv[4];

    #pragma unroll
    for (int qt = 0; qt < 4; ++qt) {
        union { bf16x8 v; uint4 r; } qu; qu.r = qraw[qt];
        const bf16x8 qf = qu.v;

        // ---- per-tile: score MFMA -> exp2 -> pack (sc never all-live) ----
        float l = 0.f;
        unsigned pw[20];
        #pragma unroll
        for (int t = 0; t < 9; ++t) {
            f32x4 sct = __builtin_amdgcn_mfma_f32_16x16x32_bf16(
                kfr[t], qf, (f32x4){0.f, 0.f, 0.f, 0.f}, 0, 0, 0);
            float e0 = fexp2(sct[0]), e1 = fexp2(sct[1]);
            float e2 = fexp2(sct[2]), e3 = fexp2(sct[3]);
            l += (e0 + e1) + (e2 + e3);
            pw[2 * t]     = pk2(e0, e1);
            pw[2 * t + 1] = pk2(e2, e3);
        }
        pw[18] = 0u; pw[19] = 0u;
        l += __shfl_xor(l, 16);
        l += __shfl_xor(l, 32);
        linv[qt] = __builtin_amdgcn_rcpf(l);

        // ---- PV: O^T = V^T . P^T, P via slot-buffer exchange ----
        *(uint4*)(PBh + slot_w) = make_uint4(pw[0], pw[1], pw[2], pw[3]);
        f32x4 oa = {0.f, 0.f, 0.f, 0.f};
        __builtin_amdgcn_s_setprio(1);
        #pragma unroll
        for (int kt2 = 0; kt2 < 5; ++kt2) {
            uint2 r1 = *(const uint2*)(PBh + slotr1);
            uint2 r2 = *(const uint2*)(PBh + slotr2);
            if (kt2 < 4)
                *(uint4*)(PBh + slot_w) =
                    make_uint4(pw[4 * kt2 + 4], pw[4 * kt2 + 5], pw[4 * kt2 + 6], pw[4 * kt2 + 7]);
            union { bf16x8 v; unsigned u[4]; } pf;
            pf.u[0] = r1.x; pf.u[1] = r1.y; pf.u[2] = r2.x; pf.u[3] = r2.y;
            oa = __builtin_amdgcn_mfma_f32_16x16x32_bf16(vfr[kt2], pf.v, oa, 0, 0, 0);
        }
        __builtin_amdgcn_s_setprio(0);
        oacc[qt] = oa;
    }
    __syncthreads();   // Klds reads done -> overlay OL

    if (grp < 2) {
        #pragma unroll
        for (int qt = 0; qt < 4; ++qt) {
            float s = linv[qt];
            uint2 ow;
            ow.x = pk2(oacc[qt][0] * s, oacc[qt][1] * s);
            ow.y = pk2(oacc[qt][2] * s, oacc[qt][3] * s);
            *(uint2*)&OL[(qt * 16 + col) * 72 + head * 8 + grp * 4] = ow;
        }
    }
    __syncthreads();

    // ---- fused epilogue: rgb = O@wcomb^T + featrgb + b_rgb (waves 0-3) ----
    if (head < 4) {
        const int qt = head;
        f32x4 acc = {0.f, 0.f, 0.f, 0.f};
        #pragma unroll
        for (int kc = 0; kc < 2; ++kc) {
            bf16x8 ao = *(const bf16x8*)&OL[(qt * 16 + col) * 72 + kc * 32 + grp * 8];
            bf16x8 bo = *(const bf16x8*)&wcombb[col * 64 + kc * 32 + grp * 8];
            acc = __builtin_amdgcn_mfma_f32_16x16x32_bf16(ao, bo, acc, 0, 0, 0);
        }
        if (col < 3) {
            float br = b_rgb[col];
            const float* frp = featrgb + ((size_t)bm * 3 + col) * HW;
            #pragma unroll
            for (int i = 0; i < 4; ++i) {
                int qs = qt * 16 + grp * 4 + i;
                int pix = (wi * 8 + (qs >> 3)) * W_IMG + wj * 8 + (qs & 7);
                outp[(size_t)bm * 3 * HW + col * HW + pix] = acc[i] + frp[pix] + br;
            }
        }
    }
}

// ---------------------------------------------------------------------------
extern "C" void kernel_launch(void* const* d_in, const int* in_sizes, int n_in,
                              void* d_out, int out_size, void* d_ws, size_t ws_size,
                              hipStream_t stream) {
    const float* x      = (const float*)d_in[0];
    const float* w_high = (const float*)d_in[1];
    const float* b_high = (const float*)d_in[2];
    const float* gamma  = (const float*)d_in[3];
    const float* beta   = (const float*)d_in[4];
    const float* w_qkv  = (const float*)d_in[5];
    const float* pos_q  = (const float*)d_in[6];
    const float* pos_k  = (const float*)d_in[7];
    const float* w_out  = (const float*)d_in[8];
    const float* w_rgb  = (const float*)d_in[9];
    const float* b_rgb  = (const float*)d_in[10];
    float* out = (float*)d_out;

    float* featrgb = (float*)d_ws;                         // [5][3][HW] f32
    short* kbuf    = (short*)(featrgb + (size_t)BM_TOT * 3 * HW);
    short* vbuf    = kbuf + (size_t)BM_TOT * HW * 64;
    short* qmid    = vbuf + (size_t)BM_TOT * HW * 64;      // [HW][64]
    short* wqkvb   = qmid + (size_t)HW * 64;               // [192][64]
    short* wcombb  = wqkvb + 192 * 64;                     // [16][64]
    float* CW      = (float*)(wcombb + 1024);              // [64][8]

    k_prep<<<1, 256, 0, stream>>>(w_qkv, w_high, b_high, gamma, beta, w_out, w_rgb,
                                  wqkvb, CW, wcombb);
    k_qkv<<<BM_TOT * 256, 256, 0, stream>>>(x, wqkvb, CW, pos_q, w_rgb,
                                            featrgb, qmid, kbuf, vbuf);
    k_attn<<<BM_TOT * 256, 512, 0, stream>>>(qmid, kbuf, vbuf, pos_k,
                                             b_rgb, featrgb, wcombb, out);
}

// Round 10
// 57.031 us; speedup vs baseline: 1.0223x; 1.0223x over previous
//
#include <hip/hip_runtime.h>
#include <hip/hip_bf16.h>

#define HW 16384
#define W_IMG 128
#define BM_TOT 5
#define PRE 0.5101179482f   // (1/sqrt(8)) * log2(e): folded into Q so p = exp2(s)

typedef __attribute__((ext_vector_type(8))) short bf16x8;
typedef __attribute__((ext_vector_type(4))) float f32x4;

__device__ __forceinline__ short f2b(float f) {
    __hip_bfloat16 h = __float2bfloat16(f);
    union { __hip_bfloat16 h; short s; } c; c.h = h; return c.s;
}
__device__ __forceinline__ float b2f(short s) {
    union { unsigned u; float f; } v; v.u = ((unsigned)(unsigned short)s) << 16;
    return v.f;
}
__device__ __forceinline__ unsigned pk2(float a, float b) {   // -> v_cvt_pk_bf16_f32
    __hip_bfloat162 h = __float22bfloat162_rn(make_float2(a, b));
    union { __hip_bfloat162 h; unsigned u; } c; c.h = h; return c.u;
}
__device__ __forceinline__ float fexp2(float x) {             // ONE v_exp_f32, no libcall
#if __has_builtin(__builtin_amdgcn_exp2f)
    return __builtin_amdgcn_exp2f(x);
#else
    float r; asm("v_exp_f32 %0, %1" : "=v"(r) : "v"(x)); return r;
#endif
}

// ---------------------------------------------------------------------------
// k_prep (1 block): weight tables.
// ---------------------------------------------------------------------------
__global__ __launch_bounds__(256) void k_prep(
    const float* __restrict__ w_qkv, const float* __restrict__ w_high,
    const float* __restrict__ b_high, const float* __restrict__ gamma,
    const float* __restrict__ beta, const float* __restrict__ w_out,
    const float* __restrict__ w_rgb,
    short* __restrict__ wqkvb, float* __restrict__ CW,
    short* __restrict__ wcombb)
{
    const int tid = threadIdx.x;
    for (int i = tid; i < 6144; i += 256)
        ((unsigned*)wqkvb)[i] = pk2(w_qkv[2 * i], w_qkv[2 * i + 1]);
    if (tid < 64) {
        float4 a = {w_high[tid * 3], w_high[tid * 3 + 1], w_high[tid * 3 + 2], b_high[tid]};
        float4 b = {gamma[tid], beta[tid], 0.f, 0.f};
        *(float4*)&CW[tid * 8] = a;
        *(float4*)&CW[tid * 8 + 4] = b;
    }
    for (int i = tid; i < 1024; i += 256) {
        short wc = 0;
        if (i < 192) {
            int c = i >> 6, e = i & 63;
            float a = 0.f;
            for (int e2 = 0; e2 < 64; ++e2)
                a = fmaf(w_rgb[c * 64 + e2], w_out[e2 * 64 + e], a);
            wc = f2b(a);
        }
        wcombb[i] = wc;
    }
}

// ---------------------------------------------------------------------------
// Kernel 1: conv+LN (4 threads/pixel, quad-shfl stats) + featRGB projection
// + MFMA 64x192 QKV projection.  (unchanged from round 8)
// ---------------------------------------------------------------------------
__global__ __launch_bounds__(256) void k_qkv(
    const float* __restrict__ x, const short* __restrict__ wqkvb,
    const float* __restrict__ CW, const float* __restrict__ pos_q,
    const float* __restrict__ w_rgb,
    float* __restrict__ featrgb, short* __restrict__ qmid,
    short* __restrict__ kbuf, short* __restrict__ vbuf)
{
    __shared__ short XS[64 * 72];
    __shared__ short TLk[64 * 72];
    __shared__ short TLv[64 * 72];
    __shared__ short TLq[64 * 72];
    __shared__ float WL[64 * 8];
    __shared__ float WRL[192];

    const int tid = threadIdx.x, blk = blockIdx.x;
    const int bm = blk >> 8, p0 = (blk & 255) * 64;
    const int pixbase = blk * 64;
    const int wv = tid >> 6, lane = tid & 63;
    const int col = lane & 15, grp = lane >> 4;

    if (tid < 128) ((float4*)WL)[tid] = ((const float4*)CW)[tid];
    else if (tid < 176) ((float4*)WRL)[tid - 128] = ((const float4*)w_rgb)[tid - 128];
    __syncthreads();

    // ---- conv + LN + rgb-residual: 4 threads/pixel, 16 channels each ----
    {
        const int px_l = tid >> 2, part = tid & 3;
        const int p = p0 + px_l;
        const float* xp = x + (size_t)bm * 3 * HW + p;
        const float x0 = xp[0], x1 = xp[HW], x2 = xp[2 * HW];
        float f[16]; float s = 0.f, s2 = 0.f;
        #pragma unroll
        for (int j = 0; j < 16; ++j) {
            const int ch = part * 16 + j;
            float4 wa = *(const float4*)&WL[ch * 8];
            f[j] = fmaf(wa.x, x0, fmaf(wa.y, x1, fmaf(wa.z, x2, wa.w)));
            s += f[j]; s2 = fmaf(f[j], f[j], s2);
        }
        float r0 = 0.f, r1 = 0.f, r2 = 0.f;
        #pragma unroll
        for (int j = 0; j < 16; ++j) {
            const float fj = f[j];
            r0 = fmaf(fj, WRL[part * 16 + j], r0);
            r1 = fmaf(fj, WRL[64 + part * 16 + j], r1);
            r2 = fmaf(fj, WRL[128 + part * 16 + j], r2);
        }
        s  += __shfl_xor(s, 1);  s  += __shfl_xor(s, 2);
        s2 += __shfl_xor(s2, 1); s2 += __shfl_xor(s2, 2);
        r0 += __shfl_xor(r0, 1); r0 += __shfl_xor(r0, 2);
        r1 += __shfl_xor(r1, 1); r1 += __shfl_xor(r1, 2);
        r2 += __shfl_xor(r2, 1); r2 += __shfl_xor(r2, 2);
        if (part < 3) {
            float rv = part == 0 ? r0 : (part == 1 ? r1 : r2);
            featrgb[((size_t)bm * 3 + part) * HW + p] = rv;
        }
        const float mu = s * 0.015625f;
        const float var = s2 * 0.015625f - mu * mu;
        const float rs = rsqrtf(var + 1e-6f);
        unsigned xw[8];
        #pragma unroll
        for (int j2 = 0; j2 < 8; ++j2) {
            const int ch = part * 16 + 2 * j2;
            float4 g0 = *(const float4*)&WL[ch * 8 + 4];
            float4 g1 = *(const float4*)&WL[ch * 8 + 12];
            xw[j2] = pk2((f[2 * j2] - mu) * rs * g0.x + g0.y,
                         (f[2 * j2 + 1] - mu) * rs * g1.x + g1.y);
        }
        *(uint4*)&XS[px_l * 72 + part * 16]     = make_uint4(xw[0], xw[1], xw[2], xw[3]);
        *(uint4*)&XS[px_l * 72 + part * 16 + 8] = make_uint4(xw[4], xw[5], xw[6], xw[7]);
    }

    // ---- B-fragments from pre-packed bf16 w_qkv ----
    bf16x8 Bf[3][2];
    #pragma unroll
    for (int jj = 0; jj < 3; ++jj) {
        int jt = wv + jj * 4;
        #pragma unroll
        for (int kc = 0; kc < 2; ++kc)
            Bf[jj][kc] = *(const bf16x8*)&wqkvb[(jt * 16 + col) * 64 + kc * 32 + grp * 8];
    }
    __syncthreads();

    // ---- MFMA projection into TL buffers ----
    #pragma unroll
    for (int pt = 0; pt < 4; ++pt) {
        bf16x8 A0 = *(const bf16x8*)&XS[(pt * 16 + col) * 72 + grp * 8];
        bf16x8 A1 = *(const bf16x8*)&XS[(pt * 16 + col) * 72 + 32 + grp * 8];

        f32x4 aK = {0.f, 0.f, 0.f, 0.f};
        aK = __builtin_amdgcn_mfma_f32_16x16x32_bf16(Bf[1][0], A0, aK, 0, 0, 0);
        aK = __builtin_amdgcn_mfma_f32_16x16x32_bf16(Bf[1][1], A1, aK, 0, 0, 0);
        uint2 kw = {pk2(aK[0], aK[1]), pk2(aK[2], aK[3])};
        *(uint2*)&TLk[(pt * 16 + col) * 72 + wv * 16 + grp * 4] = kw;

        f32x4 aV = {0.f, 0.f, 0.f, 0.f};
        aV = __builtin_amdgcn_mfma_f32_16x16x32_bf16(A0, Bf[2][0], aV, 0, 0, 0);
        aV = __builtin_amdgcn_mfma_f32_16x16x32_bf16(A1, Bf[2][1], aV, 0, 0, 0);
        #pragma unroll
        for (int i = 0; i < 4; ++i)
            TLv[(pt * 16 + grp * 4 + i) * 72 + wv * 16 + col] = f2b(aV[i]);

        if (bm == 2) {
            f32x4 aQ = {0.f, 0.f, 0.f, 0.f};
            aQ = __builtin_amdgcn_mfma_f32_16x16x32_bf16(Bf[0][0], A0, aQ, 0, 0, 0);
            aQ = __builtin_amdgcn_mfma_f32_16x16x32_bf16(Bf[0][1], A1, aQ, 0, 0, 0);
            int p = p0 + pt * 16 + col;
            int qq = ((p >> 7) & 7) * 8 + (p & 7);
            float4 pq = *(const float4*)&pos_q[qq * 64 + wv * 16 + grp * 4];
            uint2 qw = {pk2((aQ[0] + pq.x) * PRE, (aQ[1] + pq.y) * PRE),
                        pk2((aQ[2] + pq.z) * PRE, (aQ[3] + pq.w) * PRE)};
            *(uint2*)&TLq[(pt * 16 + col) * 72 + wv * 16 + grp * 4] = qw;
        }
    }
    __syncthreads();

    // ---- coalesced copy-out ----
    #pragma unroll
    for (int it = 0; it < 2; ++it) {
        int j = it * 256 + tid;
        int row = j >> 3, seg = j & 7;
        *(uint4*)&kbuf[((size_t)pixbase + row) * 64 + seg * 8] =
            *(const uint4*)&TLk[row * 72 + seg * 8];
        *(uint4*)&vbuf[((size_t)pixbase + row) * 64 + seg * 8] =
            *(const uint4*)&TLv[row * 72 + seg * 8];
        if (bm == 2)
            *(uint4*)&qmid[((size_t)p0 + row) * 64 + seg * 8] =
                *(const uint4*)&TLq[row * 72 + seg * 8];
    }
}

// ---------------------------------------------------------------------------
// Kernel 2: windowed attention + fused epilogue. 512 threads, wave = head.
// Softmax denominator computed ON THE MATRIX PIPE: PV's A-operand rows 8-15
// were duplicate/wasted, so lanes (lane&15)>=8 load a constant ONES row ->
// D[8][q] = sum_k P[k][q] = l_q. One __shfl broadcasts l; the 36-add VALU
// reduction + 2 shfl_xor + per-loop rcp chain are deleted.
// ---------------------------------------------------------------------------
__global__ __launch_bounds__(512, 6) void k_attn(
    const short* __restrict__ qmid, const short* __restrict__ kbuf,
    const short* __restrict__ vbuf,
    const float* __restrict__ pos_k, const float* __restrict__ b_rgb,
    const float* __restrict__ featrgb, const short* __restrict__ wcombb,
    float* __restrict__ outp)
{
    __shared__ char smem[48768];
    short* Klds = (short*)smem;                  // [144][72] bf16, K + pos_k
    short* Vt   = (short*)(smem + 20736);        // [65][152] bf16 (+row64=ones) + slack
    short* OL   = (short*)smem;                  // overlay after attention
    // P slot buffers: smem + 40528, 1 KB per wave (8 waves)

    const int tid = threadIdx.x, blk = blockIdx.x;
    const int bm = blk >> 8, widx = blk & 255;
    const int wi = widx >> 4, wj = widx & 15;
    const int head = tid >> 6, lane = tid & 63;
    const int col = lane & 15, grp = lane >> 4;

    // ---- stage K(+pos_k): key-fast -> coalesced reads ----
    for (int idx = tid; idx < 1152; idx += 512) {
        int kk = idx >> 3, chunk = idx & 7;
        int r = kk / 12, c = kk - r * 12;
        int hh = wi * 8 - 2 + r, ww = wj * 8 - 2 + c;
        uint4 kraw = {0, 0, 0, 0};
        if ((unsigned)hh < 128u && (unsigned)ww < 128u)
            kraw = *(const uint4*)&kbuf[((size_t)bm * HW + hh * W_IMG + ww) * 64 + chunk * 8];
        const float* pk = &pos_k[kk * 64 + chunk * 8];
        float4 pk0 = *(const float4*)pk;
        float4 pk1 = *(const float4*)(pk + 4);
        union { uint4 q; short s[8]; } ku; ku.q = kraw;
        uint4 ko;
        ko.x = pk2(b2f(ku.s[0]) + pk0.x, b2f(ku.s[1]) + pk0.y);
        ko.y = pk2(b2f(ku.s[2]) + pk0.z, b2f(ku.s[3]) + pk0.w);
        ko.z = pk2(b2f(ku.s[4]) + pk1.x, b2f(ku.s[5]) + pk1.y);
        ko.w = pk2(b2f(ku.s[6]) + pk1.z, b2f(ku.s[7]) + pk1.w);
        *(uint4*)&Klds[kk * 72 + chunk * 8] = ko;
    }

    // ---- stage V^T: chunk-major ----
    for (int idx = tid; idx < 1152; idx += 512) {
        int chunk = idx / 144, kk = idx - chunk * 144;
        int r = kk / 12, c = kk - r * 12;
        int hh = wi * 8 - 2 + r, ww = wj * 8 - 2 + c;
        uint4 vraw = {0, 0, 0, 0};
        if ((unsigned)hh < 128u && (unsigned)ww < 128u)
            vraw = *(const uint4*)&vbuf[((size_t)bm * HW + hh * W_IMG + ww) * 64 + chunk * 8];
        union { uint4 q; short s[8]; } vu; vu.q = vraw;
        #pragma unroll
        for (int cc = 0; cc < 8; ++cc)
            Vt[(chunk * 8 + cc) * 152 + kk] = vu.s[cc];
    }
    // zero pad cols [144,152) of real rows; ONES row 64 (168 shorts incl. slack)
    if (tid < 64) *(uint4*)&Vt[tid * 152 + 144] = (uint4){0, 0, 0, 0};
    if (tid < 84) ((unsigned*)(Vt + 64 * 152))[tid] = 0x3f803f80u;

    // ---- Q fragments (pos_q & scale pre-folded) ----
    uint4 qraw[4] = {{0,0,0,0},{0,0,0,0},{0,0,0,0},{0,0,0,0}};
    if (grp == 0) {
        #pragma unroll
        for (int qt = 0; qt < 4; ++qt) {
            int q = qt * 16 + col;
            int pix = (wi * 8 + (q >> 3)) * W_IMG + wj * 8 + (q & 7);
            qraw[qt] = *(const uint4*)&qmid[(size_t)pix * 64 + head * 8];
        }
    }
    __syncthreads();

    unsigned* PBh = (unsigned*)(smem + 40528 + head * 1024);
    const int slot_w = (grp * 16 + (col ^ grp)) * 4;
    const int g0 = 2 * (grp & 1);
    const int slotr1 = (g0 * 16 + (col ^ g0)) * 4 + (grp >> 1) * 2;
    const int slotr2 = ((g0 + 1) * 16 + (col ^ (g0 + 1))) * 4 + (grp >> 1) * 2;
    // PV A-operand row: real V channels for lanes 0-7 of each 16-group,
    // the ONES row (64) for lanes 8-15 -> D[8][q] = l_q on the matrix pipe.
    const int vrow = ((lane & 15) < 8) ? (head * 8 + (lane & 7)) : 64;

    f32x4 oacc[4];

    #pragma unroll
    for (int qt = 0; qt < 4; ++qt) {
        union { bf16x8 v; uint4 r; } qu; qu.r = qraw[qt];
        const bf16x8 qf = qu.v;

        // ---- scores S^T -> exp2 -> pack (no denominator VALU work) ----
        unsigned pw[20];
        __builtin_amdgcn_s_setprio(1);
        #pragma unroll
        for (int t = 0; t < 9; ++t) {
            bf16x8 kf = *(const bf16x8*)&Klds[(t * 16 + col) * 72 + head * 8];
            f32x4 sct = __builtin_amdgcn_mfma_f32_16x16x32_bf16(
                kf, qf, (f32x4){0.f, 0.f, 0.f, 0.f}, 0, 0, 0);
            pw[2 * t]     = pk2(fexp2(sct[0]), fexp2(sct[1]));
            pw[2 * t + 1] = pk2(fexp2(sct[2]), fexp2(sct[3]));
        }
        __builtin_amdgcn_s_setprio(0);
        pw[18] = 0u; pw[19] = 0u;

        // ---- PV: O^T = V^T . P^T (+ ones-row -> l in D row 8) ----
        *(uint4*)(PBh + slot_w) = make_uint4(pw[0], pw[1], pw[2], pw[3]);
        f32x4 oa = {0.f, 0.f, 0.f, 0.f};
        __builtin_amdgcn_s_setprio(1);
        #pragma unroll
        for (int kt2 = 0; kt2 < 5; ++kt2) {
            uint2 r1 = *(const uint2*)(PBh + slotr1);
            uint2 r2 = *(const uint2*)(PBh + slotr2);
            if (kt2 < 4)
                *(uint4*)(PBh + slot_w) =
                    make_uint4(pw[4 * kt2 + 4], pw[4 * kt2 + 5], pw[4 * kt2 + 6], pw[4 * kt2 + 7]);
            union { bf16x8 v; unsigned u[4]; } pf;
            pf.u[0] = r1.x; pf.u[1] = r1.y; pf.u[2] = r2.x; pf.u[3] = r2.y;
            bf16x8 vf = *(const bf16x8*)&Vt[vrow * 152 + kt2 * 32 + grp * 8];
            oa = __builtin_amdgcn_mfma_f32_16x16x32_bf16(vf, pf.v, oa, 0, 0, 0);
        }
        __builtin_amdgcn_s_setprio(0);
        oacc[qt] = oa;
    }

    // ---- broadcast l (lives in D row 8 = lanes 32..47, reg 0) ----
    float lq[4];
    #pragma unroll
    for (int qt = 0; qt < 4; ++qt)
        lq[qt] = __shfl(oacc[qt][0], 32 + col);

    __syncthreads();   // Klds reads done -> overlay OL

    if (grp < 2) {
        #pragma unroll
        for (int qt = 0; qt < 4; ++qt) {
            float s = __builtin_amdgcn_rcpf(lq[qt]);
            uint2 ow;
            ow.x = pk2(oacc[qt][0] * s, oacc[qt][1] * s);
            ow.y = pk2(oacc[qt][2] * s, oacc[qt][3] * s);
            *(uint2*)&OL[(qt * 16 + col) * 72 + head * 8 + grp * 4] = ow;
        }
    }
    __syncthreads();

    // ---- fused epilogue: rgb = O@wcomb^T + featrgb + b_rgb (waves 0-3) ----
    if (head < 4) {
        const int qt = head;
        f32x4 acc = {0.f, 0.f, 0.f, 0.f};
        #pragma unroll
        for (int kc = 0; kc < 2; ++kc) {
            bf16x8 ao = *(const bf16x8*)&OL[(qt * 16 + col) * 72 + kc * 32 + grp * 8];
            bf16x8 bo = *(const bf16x8*)&wcombb[col * 64 + kc * 32 + grp * 8];
            acc = __builtin_amdgcn_mfma_f32_16x16x32_bf16(ao, bo, acc, 0, 0, 0);
        }
        if (col < 3) {
            float br = b_rgb[col];
            const float* frp = featrgb + ((size_t)bm * 3 + col) * HW;
            #pragma unroll
            for (int i = 0; i < 4; ++i) {
                int qs = qt * 16 + grp * 4 + i;
                int pix = (wi * 8 + (qs >> 3)) * W_IMG + wj * 8 + (qs & 7);
                outp[(size_t)bm * 3 * HW + col * HW + pix] = acc[i] + frp[pix] + br;
            }
        }
    }
}

// ---------------------------------------------------------------------------
extern "C" void kernel_launch(void* const* d_in, const int* in_sizes, int n_in,
                              void* d_out, int out_size, void* d_ws, size_t ws_size,
                              hipStream_t stream) {
    const float* x      = (const float*)d_in[0];
    const float* w_high = (const float*)d_in[1];
    const float* b_high = (const float*)d_in[2];
    const float* gamma  = (const float*)d_in[3];
    const float* beta   = (const float*)d_in[4];
    const float* w_qkv  = (const float*)d_in[5];
    const float* pos_q  = (const float*)d_in[6];
    const float* pos_k  = (const float*)d_in[7];
    const float* w_out  = (const float*)d_in[8];
    const float* w_rgb  = (const float*)d_in[9];
    const float* b_rgb  = (const float*)d_in[10];
    float* out = (float*)d_out;

    float* featrgb = (float*)d_ws;                         // [5][3][HW] f32
    short* kbuf    = (short*)(featrgb + (size_t)BM_TOT * 3 * HW);
    short* vbuf    = kbuf + (size_t)BM_TOT * HW * 64;
    short* qmid    = vbuf + (size_t)BM_TOT * HW * 64;      // [HW][64]
    short* wqkvb   = qmid + (size_t)HW * 64;               // [192][64]
    short* wcombb  = wqkvb + 192 * 64;                     // [16][64]
    float* CW      = (float*)(wcombb + 1024);              // [64][8]

    k_prep<<<1, 256, 0, stream>>>(w_qkv, w_high, b_high, gamma, beta, w_out, w_rgb,
                                  wqkvb, CW, wcombb);
    k_qkv<<<BM_TOT * 256, 256, 0, stream>>>(x, wqkvb, CW, pos_q, w_rgb,
                                            featrgb, qmid, kbuf, vbuf);
    k_attn<<<BM_TOT * 256, 512, 0, stream>>>(qmid, kbuf, vbuf, pos_k,
                                             b_rgb, featrgb, wcombb, out);
}

// Round 11
// 55.345 us; speedup vs baseline: 1.0534x; 1.0305x over previous
//
#include <hip/hip_runtime.h>
#include <hip/hip_bf16.h>

#define HW 16384
#define W_IMG 128
#define BM_TOT 5
#define PRE 0.5101179482f   // (1/sqrt(8)) * log2(e): folded into Q so p = exp2(s)

typedef __attribute__((ext_vector_type(8))) short bf16x8;
typedef __attribute__((ext_vector_type(4))) float f32x4;

__device__ __forceinline__ short f2b(float f) {
    __hip_bfloat16 h = __float2bfloat16(f);
    union { __hip_bfloat16 h; short s; } c; c.h = h; return c.s;
}
__device__ __forceinline__ float b2f(short s) {
    union { unsigned u; float f; } v; v.u = ((unsigned)(unsigned short)s) << 16;
    return v.f;
}
__device__ __forceinline__ unsigned pk2(float a, float b) {   // -> v_cvt_pk_bf16_f32
    __hip_bfloat162 h = __float22bfloat162_rn(make_float2(a, b));
    union { __hip_bfloat162 h; unsigned u; } c; c.h = h; return c.u;
}
__device__ __forceinline__ float fexp2(float x) {             // ONE v_exp_f32, no libcall
#if __has_builtin(__builtin_amdgcn_exp2f)
    return __builtin_amdgcn_exp2f(x);
#else
    float r; asm("v_exp_f32 %0, %1" : "=v"(r) : "v"(x)); return r;
#endif
}

// ---------------------------------------------------------------------------
// Kernel 1: conv+LN (4 threads/pixel, quad-shfl stats) + featRGB projection
// + MFMA 64x192 QKV projection. All weight prep in-kernel (NO serial k_prep):
// conv/LN table + w_rgb staged per block; B-frags packed from f32 w_qkv.
// Block 0 tail computes wcomb = w_rgb @ w_out via LDS-staged w_out (the
// latency-hidden replacement for the old serial k_prep kernel).
// ---------------------------------------------------------------------------
__global__ __launch_bounds__(256) void k_qkv(
    const float* __restrict__ x, const float* __restrict__ w_qkv,
    const float* __restrict__ w_high, const float* __restrict__ b_high,
    const float* __restrict__ gamma, const float* __restrict__ beta,
    const float* __restrict__ pos_q, const float* __restrict__ w_rgb,
    const float* __restrict__ w_out,
    float* __restrict__ featrgb, short* __restrict__ qmid,
    short* __restrict__ kbuf, short* __restrict__ vbuf,
    short* __restrict__ wcombb)
{
    __shared__ char smem[39680];
    short* XS  = (short*)smem;                 // [64][72] bf16 normalized acts
    short* TLk = (short*)(smem + 9216);        // [64][72] staging
    short* TLv = (short*)(smem + 18432);
    short* TLq = (short*)(smem + 27648);
    float* WL  = (float*)(smem + 36864);       // [64][8] conv/LN table
    float* WRL = (float*)(smem + 36864 + 2048);// [192] w_rgb

    const int tid = threadIdx.x, blk = blockIdx.x;
    const int bm = blk >> 8, p0 = (blk & 255) * 64;
    const int pixbase = blk * 64;
    const int wv = tid >> 6, lane = tid & 63;
    const int col = lane & 15, grp = lane >> 4;

    // ---- build weight tables in LDS (tiny, L2-hot) ----
    if (tid < 64) {
        WL[tid * 8 + 0] = w_high[tid * 3];
        WL[tid * 8 + 1] = w_high[tid * 3 + 1];
        WL[tid * 8 + 2] = w_high[tid * 3 + 2];
        WL[tid * 8 + 3] = b_high[tid];
        WL[tid * 8 + 4] = gamma[tid];
        WL[tid * 8 + 5] = beta[tid];
    } else if (tid < 112) {
        ((float4*)WRL)[tid - 64] = ((const float4*)w_rgb)[tid - 64];
    }
    __syncthreads();

    // ---- conv + LN + rgb-residual: 4 threads/pixel, 16 channels each ----
    {
        const int px_l = tid >> 2, part = tid & 3;
        const int p = p0 + px_l;
        const float* xp = x + (size_t)bm * 3 * HW + p;
        const float x0 = xp[0], x1 = xp[HW], x2 = xp[2 * HW];
        float f[16]; float s = 0.f, s2 = 0.f;
        #pragma unroll
        for (int j = 0; j < 16; ++j) {
            const int ch = part * 16 + j;
            float4 wa = *(const float4*)&WL[ch * 8];
            f[j] = fmaf(wa.x, x0, fmaf(wa.y, x1, fmaf(wa.z, x2, wa.w)));
            s += f[j]; s2 = fmaf(f[j], f[j], s2);
        }
        float r0 = 0.f, r1 = 0.f, r2 = 0.f;
        #pragma unroll
        for (int j = 0; j < 16; ++j) {
            const float fj = f[j];
            r0 = fmaf(fj, WRL[part * 16 + j], r0);
            r1 = fmaf(fj, WRL[64 + part * 16 + j], r1);
            r2 = fmaf(fj, WRL[128 + part * 16 + j], r2);
        }
        s  += __shfl_xor(s, 1);  s  += __shfl_xor(s, 2);
        s2 += __shfl_xor(s2, 1); s2 += __shfl_xor(s2, 2);
        r0 += __shfl_xor(r0, 1); r0 += __shfl_xor(r0, 2);
        r1 += __shfl_xor(r1, 1); r1 += __shfl_xor(r1, 2);
        r2 += __shfl_xor(r2, 1); r2 += __shfl_xor(r2, 2);
        if (part < 3) {
            float rv = part == 0 ? r0 : (part == 1 ? r1 : r2);
            featrgb[((size_t)bm * 3 + part) * HW + p] = rv;
        }
        const float mu = s * 0.015625f;
        const float var = s2 * 0.015625f - mu * mu;
        const float rs = rsqrtf(var + 1e-6f);
        unsigned xw[8];
        #pragma unroll
        for (int j2 = 0; j2 < 8; ++j2) {
            const int ch = part * 16 + 2 * j2;
            float4 g0 = *(const float4*)&WL[ch * 8 + 4];
            float4 g1 = *(const float4*)&WL[ch * 8 + 12];
            xw[j2] = pk2((f[2 * j2] - mu) * rs * g0.x + g0.y,
                         (f[2 * j2 + 1] - mu) * rs * g1.x + g1.y);
        }
        *(uint4*)&XS[px_l * 72 + part * 16]     = make_uint4(xw[0], xw[1], xw[2], xw[3]);
        *(uint4*)&XS[px_l * 72 + part * 16 + 8] = make_uint4(xw[4], xw[5], xw[6], xw[7]);
    }

    // ---- B-fragments packed from f32 w_qkv (L2-hot, r5-proven pattern) ----
    bf16x8 Bf[3][2];
    #pragma unroll
    for (int jj = 0; jj < 3; ++jj) {
        int jt = wv + jj * 4;
        #pragma unroll
        for (int kc = 0; kc < 2; ++kc) {
            const float* src = &w_qkv[(jt * 16 + col) * 64 + kc * 32 + grp * 8];
            union { bf16x8 v; unsigned u[4]; } tmp;
            #pragma unroll
            for (int i = 0; i < 4; ++i) tmp.u[i] = pk2(src[2 * i], src[2 * i + 1]);
            Bf[jj][kc] = tmp.v;
        }
    }
    __syncthreads();

    // ---- MFMA projection into TL buffers ----
    #pragma unroll
    for (int pt = 0; pt < 4; ++pt) {
        bf16x8 A0 = *(const bf16x8*)&XS[(pt * 16 + col) * 72 + grp * 8];
        bf16x8 A1 = *(const bf16x8*)&XS[(pt * 16 + col) * 72 + 32 + grp * 8];

        f32x4 aK = {0.f, 0.f, 0.f, 0.f};
        aK = __builtin_amdgcn_mfma_f32_16x16x32_bf16(Bf[1][0], A0, aK, 0, 0, 0);
        aK = __builtin_amdgcn_mfma_f32_16x16x32_bf16(Bf[1][1], A1, aK, 0, 0, 0);
        uint2 kw = {pk2(aK[0], aK[1]), pk2(aK[2], aK[3])};
        *(uint2*)&TLk[(pt * 16 + col) * 72 + wv * 16 + grp * 4] = kw;

        f32x4 aV = {0.f, 0.f, 0.f, 0.f};
        aV = __builtin_amdgcn_mfma_f32_16x16x32_bf16(A0, Bf[2][0], aV, 0, 0, 0);
        aV = __builtin_amdgcn_mfma_f32_16x16x32_bf16(A1, Bf[2][1], aV, 0, 0, 0);
        #pragma unroll
        for (int i = 0; i < 4; ++i)
            TLv[(pt * 16 + grp * 4 + i) * 72 + wv * 16 + col] = f2b(aV[i]);

        if (bm == 2) {
            f32x4 aQ = {0.f, 0.f, 0.f, 0.f};
            aQ = __builtin_amdgcn_mfma_f32_16x16x32_bf16(Bf[0][0], A0, aQ, 0, 0, 0);
            aQ = __builtin_amdgcn_mfma_f32_16x16x32_bf16(Bf[0][1], A1, aQ, 0, 0, 0);
            int p = p0 + pt * 16 + col;
            int qq = ((p >> 7) & 7) * 8 + (p & 7);
            float4 pq = *(const float4*)&pos_q[qq * 64 + wv * 16 + grp * 4];
            uint2 qw = {pk2((aQ[0] + pq.x) * PRE, (aQ[1] + pq.y) * PRE),
                        pk2((aQ[2] + pq.z) * PRE, (aQ[3] + pq.w) * PRE)};
            *(uint2*)&TLq[(pt * 16 + col) * 72 + wv * 16 + grp * 4] = qw;
        }
    }
    __syncthreads();

    // ---- coalesced copy-out ----
    #pragma unroll
    for (int it = 0; it < 2; ++it) {
        int j = it * 256 + tid;
        int row = j >> 3, seg = j & 7;
        *(uint4*)&kbuf[((size_t)pixbase + row) * 64 + seg * 8] =
            *(const uint4*)&TLk[row * 72 + seg * 8];
        *(uint4*)&vbuf[((size_t)pixbase + row) * 64 + seg * 8] =
            *(const uint4*)&TLv[row * 72 + seg * 8];
        if (bm == 2)
            *(uint4*)&qmid[((size_t)p0 + row) * 64 + seg * 8] =
                *(const uint4*)&TLq[row * 72 + seg * 8];
    }

    // ---- block 0 tail: wcomb = w_rgb @ w_out via LDS-staged w_out ----
    if (blk == 0) {
        float* WOL = (float*)TLk;           // 18.4 KB region, need 16 KB
        __syncthreads();                    // copy-out reads of TLk/TLv done
        for (int i = tid; i < 4096; i += 256) WOL[i] = w_out[i];
        __syncthreads();
        for (int i = tid; i < 1024; i += 256) {
            short wc = 0;
            if (i < 192) {
                int c = i >> 6, e = i & 63;
                float a = 0.f;
                #pragma unroll 8
                for (int e2 = 0; e2 < 64; ++e2)
                    a = fmaf(WRL[c * 64 + e2], WOL[e2 * 64 + e], a);
                wc = f2b(a);
            }
            wcombb[i] = wc;
        }
    }
}

// ---------------------------------------------------------------------------
// Kernel 2: windowed attention + fused epilogue (round-8 kernel, verbatim —
// best measured; r9 reg-hoist and r10 ones-row variants both reverted).
// ---------------------------------------------------------------------------
__global__ __launch_bounds__(512, 6) void k_attn(
    const short* __restrict__ qmid, const short* __restrict__ kbuf,
    const short* __restrict__ vbuf,
    const float* __restrict__ pos_k, const float* __restrict__ b_rgb,
    const float* __restrict__ featrgb, const short* __restrict__ wcombb,
    float* __restrict__ outp)
{
    __shared__ char smem[48448];
    short* Klds = (short*)smem;                  // [144][72] bf16, K + pos_k
    short* Vt   = (short*)(smem + 20736);        // [64][152] bf16 + slack
    short* OL   = (short*)smem;                  // overlay after attention
    // P slot buffers: smem + 40224, 1 KB per wave (8 waves)

    const int tid = threadIdx.x, blk = blockIdx.x;
    const int bm = blk >> 8, widx = blk & 255;
    const int wi = widx >> 4, wj = widx & 15;
    const int head = tid >> 6, lane = tid & 63;
    const int col = lane & 15, grp = lane >> 4;

    // ---- stage K(+pos_k): key-fast -> coalesced reads ----
    for (int idx = tid; idx < 1152; idx += 512) {
        int kk = idx >> 3, chunk = idx & 7;
        int r = kk / 12, c = kk - r * 12;
        int hh = wi * 8 - 2 + r, ww = wj * 8 - 2 + c;
        uint4 kraw = {0, 0, 0, 0};
        if ((unsigned)hh < 128u && (unsigned)ww < 128u)
            kraw = *(const uint4*)&kbuf[((size_t)bm * HW + hh * W_IMG + ww) * 64 + chunk * 8];
        const float* pk = &pos_k[kk * 64 + chunk * 8];
        float4 pk0 = *(const float4*)pk;
        float4 pk1 = *(const float4*)(pk + 4);
        union { uint4 q; short s[8]; } ku; ku.q = kraw;
        uint4 ko;
        ko.x = pk2(b2f(ku.s[0]) + pk0.x, b2f(ku.s[1]) + pk0.y);
        ko.y = pk2(b2f(ku.s[2]) + pk0.z, b2f(ku.s[3]) + pk0.w);
        ko.z = pk2(b2f(ku.s[4]) + pk1.x, b2f(ku.s[5]) + pk1.y);
        ko.w = pk2(b2f(ku.s[6]) + pk1.z, b2f(ku.s[7]) + pk1.w);
        *(uint4*)&Klds[kk * 72 + chunk * 8] = ko;
    }

    // ---- stage V^T: chunk-major ----
    for (int idx = tid; idx < 1152; idx += 512) {
        int chunk = idx / 144, kk = idx - chunk * 144;
        int r = kk / 12, c = kk - r * 12;
        int hh = wi * 8 - 2 + r, ww = wj * 8 - 2 + c;
        uint4 vraw = {0, 0, 0, 0};
        if ((unsigned)hh < 128u && (unsigned)ww < 128u)
            vraw = *(const uint4*)&vbuf[((size_t)bm * HW + hh * W_IMG + ww) * 64 + chunk * 8];
        union { uint4 q; short s[8]; } vu; vu.q = vraw;
        #pragma unroll
        for (int cc = 0; cc < 8; ++cc)
            Vt[(chunk * 8 + cc) * 152 + kk] = vu.s[cc];
    }
    if (tid < 64) *(uint4*)&Vt[tid * 152 + 144] = (uint4){0, 0, 0, 0};
    if (tid < 2)  *(uint4*)&Vt[64 * 152 + tid * 8] = (uint4){0, 0, 0, 0};

    // ---- Q fragments (pos_q & scale pre-folded) ----
    uint4 qraw[4] = {{0,0,0,0},{0,0,0,0},{0,0,0,0},{0,0,0,0}};
    if (grp == 0) {
        #pragma unroll
        for (int qt = 0; qt < 4; ++qt) {
            int q = qt * 16 + col;
            int pix = (wi * 8 + (q >> 3)) * W_IMG + wj * 8 + (q & 7);
            qraw[qt] = *(const uint4*)&qmid[(size_t)pix * 64 + head * 8];
        }
    }
    __syncthreads();

    unsigned* PBh = (unsigned*)(smem + 40224 + head * 1024);
    const int slot_w = (grp * 16 + (col ^ grp)) * 4;
    const int g0 = 2 * (grp & 1);
    const int slotr1 = (g0 * 16 + (col ^ g0)) * 4 + (grp >> 1) * 2;
    const int slotr2 = ((g0 + 1) * 16 + (col ^ (g0 + 1))) * 4 + (grp >> 1) * 2;

    f32x4 oacc[4];
    float linv[4];

    #pragma unroll
    for (int qt = 0; qt < 4; ++qt) {
        union { bf16x8 v; uint4 r; } qu; qu.r = qraw[qt];
        const bf16x8 qf = qu.v;

        // ---- softmax, no max-subtract: p = exp2(s) directly ----
        float l = 0.f;
        unsigned pw[20];
        __builtin_amdgcn_s_setprio(1);
        #pragma unroll
        for (int t = 0; t < 9; ++t) {
            bf16x8 kf = *(const bf16x8*)&Klds[(t * 16 + col) * 72 + head * 8];
            f32x4 sct = __builtin_amdgcn_mfma_f32_16x16x32_bf16(
                kf, qf, (f32x4){0.f, 0.f, 0.f, 0.f}, 0, 0, 0);
            float e0 = fexp2(sct[0]), e1 = fexp2(sct[1]);
            float e2 = fexp2(sct[2]), e3 = fexp2(sct[3]);
            l += (e0 + e1) + (e2 + e3);
            pw[2 * t]     = pk2(e0, e1);
            pw[2 * t + 1] = pk2(e2, e3);
        }
        __builtin_amdgcn_s_setprio(0);
        pw[18] = 0u; pw[19] = 0u;
        l += __shfl_xor(l, 16);
        l += __shfl_xor(l, 32);
        linv[qt] = __builtin_amdgcn_rcpf(l);

        // ---- PV: O^T = V^T . P^T, P via slot-buffer exchange ----
        *(uint4*)(PBh + slot_w) = make_uint4(pw[0], pw[1], pw[2], pw[3]);
        f32x4 oa = {0.f, 0.f, 0.f, 0.f};
        __builtin_amdgcn_s_setprio(1);
        #pragma unroll
        for (int kt2 = 0; kt2 < 5; ++kt2) {
            uint2 r1 = *(const uint2*)(PBh + slotr1);
            uint2 r2 = *(const uint2*)(PBh + slotr2);
            if (kt2 < 4)
                *(uint4*)(PBh + slot_w) =
                    make_uint4(pw[4 * kt2 + 4], pw[4 * kt2 + 5], pw[4 * kt2 + 6], pw[4 * kt2 + 7]);
            union { bf16x8 v; unsigned u[4]; } pf;
            pf.u[0] = r1.x; pf.u[1] = r1.y; pf.u[2] = r2.x; pf.u[3] = r2.y;
            bf16x8 vf = *(const bf16x8*)&Vt[(head * 8 + (lane & 7)) * 152 + kt2 * 32 + grp * 8];
            oa = __builtin_amdgcn_mfma_f32_16x16x32_bf16(vf, pf.v, oa, 0, 0, 0);
        }
        __builtin_amdgcn_s_setprio(0);
        oacc[qt] = oa;
    }
    __syncthreads();   // Klds reads done -> overlay OL

    if (grp < 2) {
        #pragma unroll
        for (int qt = 0; qt < 4; ++qt) {
            float s = linv[qt];
            uint2 ow;
            ow.x = pk2(oacc[qt][0] * s, oacc[qt][1] * s);
            ow.y = pk2(oacc[qt][2] * s, oacc[qt][3] * s);
            *(uint2*)&OL[(qt * 16 + col) * 72 + head * 8 + grp * 4] = ow;
        }
    }
    __syncthreads();

    // ---- fused epilogue: rgb = O@wcomb^T + featrgb + b_rgb (waves 0-3) ----
    if (head < 4) {
        const int qt = head;
        f32x4 acc = {0.f, 0.f, 0.f, 0.f};
        #pragma unroll
        for (int kc = 0; kc < 2; ++kc) {
            bf16x8 ao = *(const bf16x8*)&OL[(qt * 16 + col) * 72 + kc * 32 + grp * 8];
            bf16x8 bo = *(const bf16x8*)&wcombb[col * 64 + kc * 32 + grp * 8];
            acc = __builtin_amdgcn_mfma_f32_16x16x32_bf16(ao, bo, acc, 0, 0, 0);
        }
        if (col < 3) {
            float br = b_rgb[col];
            const float* frp = featrgb + ((size_t)bm * 3 + col) * HW;
            #pragma unroll
            for (int i = 0; i < 4; ++i) {
                int qs = qt * 16 + grp * 4 + i;
                int pix = (wi * 8 + (qs >> 3)) * W_IMG + wj * 8 + (qs & 7);
                outp[(size_t)bm * 3 * HW + col * HW + pix] = acc[i] + frp[pix] + br;
            }
        }
    }
}

// ---------------------------------------------------------------------------
extern "C" void kernel_launch(void* const* d_in, const int* in_sizes, int n_in,
                              void* d_out, int out_size, void* d_ws, size_t ws_size,
                              hipStream_t stream) {
    const float* x      = (const float*)d_in[0];
    const float* w_high = (const float*)d_in[1];
    const float* b_high = (const float*)d_in[2];
    const float* gamma  = (const float*)d_in[3];
    const float* beta   = (const float*)d_in[4];
    const float* w_qkv  = (const float*)d_in[5];
    const float* pos_q  = (const float*)d_in[6];
    const float* pos_k  = (const float*)d_in[7];
    const float* w_out  = (const float*)d_in[8];
    const float* w_rgb  = (const float*)d_in[9];
    const float* b_rgb  = (const float*)d_in[10];
    float* out = (float*)d_out;

    float* featrgb = (float*)d_ws;                         // [5][3][HW] f32
    short* kbuf    = (short*)(featrgb + (size_t)BM_TOT * 3 * HW);
    short* vbuf    = kbuf + (size_t)BM_TOT * HW * 64;
    short* qmid    = vbuf + (size_t)BM_TOT * HW * 64;      // [HW][64]
    short* wcombb  = qmid + (size_t)HW * 64;               // [16][64]

    k_qkv<<<BM_TOT * 256, 256, 0, stream>>>(x, w_qkv, w_high, b_high, gamma, beta,
                                            pos_q, w_rgb, w_out,
                                            featrgb, qmid, kbuf, vbuf, wcombb);
    k_attn<<<BM_TOT * 256, 512, 0, stream>>>(qmid, kbuf, vbuf, pos_k,
                                             b_rgb, featrgb, wcombb, out);
}

// Round 12
// 54.848 us; speedup vs baseline: 1.0630x; 1.0091x over previous
//
#include <hip/hip_runtime.h>
#include <hip/hip_bf16.h>

#define HW 16384
#define W_IMG 128
#define BM_TOT 5
#define PRE 0.5101179482f   // (1/sqrt(8)) * log2(e): folded into Q so p = exp2(s)

typedef __attribute__((ext_vector_type(8))) short bf16x8;
typedef __attribute__((ext_vector_type(4))) float f32x4;

__device__ __forceinline__ short f2b(float f) {
    __hip_bfloat16 h = __float2bfloat16(f);
    union { __hip_bfloat16 h; short s; } c; c.h = h; return c.s;
}
__device__ __forceinline__ float b2f(short s) {
    union { unsigned u; float f; } v; v.u = ((unsigned)(unsigned short)s) << 16;
    return v.f;
}
__device__ __forceinline__ unsigned pk2(float a, float b) {   // -> v_cvt_pk_bf16_f32
    __hip_bfloat162 h = __float22bfloat162_rn(make_float2(a, b));
    union { __hip_bfloat162 h; unsigned u; } c; c.h = h; return c.u;
}
__device__ __forceinline__ float fexp2(float x) {             // ONE v_exp_f32, no libcall
#if __has_builtin(__builtin_amdgcn_exp2f)
    return __builtin_amdgcn_exp2f(x);
#else
    float r; asm("v_exp_f32 %0, %1" : "=v"(r) : "v"(x)); return r;
#endif
}

// ---------------------------------------------------------------------------
// Kernel 1: conv+LN (4 threads/pixel, quad-shfl stats) + featRGB projection
// + MFMA 64x192 QKV projection. Weight prep in-kernel; B-frags packed with
// float4 loads. Block 0 tail computes wcomb via LDS-staged w_out.
// ---------------------------------------------------------------------------
__global__ __launch_bounds__(256) void k_qkv(
    const float* __restrict__ x, const float* __restrict__ w_qkv,
    const float* __restrict__ w_high, const float* __restrict__ b_high,
    const float* __restrict__ gamma, const float* __restrict__ beta,
    const float* __restrict__ pos_q, const float* __restrict__ w_rgb,
    const float* __restrict__ w_out,
    float* __restrict__ featrgb, short* __restrict__ qmid,
    short* __restrict__ kbuf, short* __restrict__ vbuf,
    short* __restrict__ wcombb)
{
    __shared__ char smem[39680];
    short* XS  = (short*)smem;                 // [64][72] bf16 normalized acts
    short* TLk = (short*)(smem + 9216);        // [64][72] staging
    short* TLv = (short*)(smem + 18432);
    short* TLq = (short*)(smem + 27648);
    float* WL  = (float*)(smem + 36864);       // [64][8] conv/LN table
    float* WRL = (float*)(smem + 36864 + 2048);// [192] w_rgb

    const int tid = threadIdx.x, blk = blockIdx.x;
    const int bm = blk >> 8, p0 = (blk & 255) * 64;
    const int pixbase = blk * 64;
    const int wv = tid >> 6, lane = tid & 63;
    const int col = lane & 15, grp = lane >> 4;

    // ---- issue x loads FIRST (independent of LDS tables) ----
    const int px_l = tid >> 2, part = tid & 3;
    const int p_glob = p0 + px_l;
    const float* xp = x + (size_t)bm * 3 * HW + p_glob;
    const float x0 = xp[0], x1 = xp[HW], x2 = xp[2 * HW];

    // ---- build weight tables in LDS (tiny, L2-hot) ----
    if (tid < 64) {
        WL[tid * 8 + 0] = w_high[tid * 3];
        WL[tid * 8 + 1] = w_high[tid * 3 + 1];
        WL[tid * 8 + 2] = w_high[tid * 3 + 2];
        WL[tid * 8 + 3] = b_high[tid];
        WL[tid * 8 + 4] = gamma[tid];
        WL[tid * 8 + 5] = beta[tid];
    } else if (tid < 112) {
        ((float4*)WRL)[tid - 64] = ((const float4*)w_rgb)[tid - 64];
    }
    __syncthreads();

    // ---- conv + LN + rgb-residual: 4 threads/pixel, 16 channels each ----
    {
        float f[16]; float s = 0.f, s2 = 0.f;
        #pragma unroll
        for (int j = 0; j < 16; ++j) {
            const int ch = part * 16 + j;
            float4 wa = *(const float4*)&WL[ch * 8];
            f[j] = fmaf(wa.x, x0, fmaf(wa.y, x1, fmaf(wa.z, x2, wa.w)));
            s += f[j]; s2 = fmaf(f[j], f[j], s2);
        }
        float r0 = 0.f, r1 = 0.f, r2 = 0.f;
        #pragma unroll
        for (int j = 0; j < 16; ++j) {
            const float fj = f[j];
            r0 = fmaf(fj, WRL[part * 16 + j], r0);
            r1 = fmaf(fj, WRL[64 + part * 16 + j], r1);
            r2 = fmaf(fj, WRL[128 + part * 16 + j], r2);
        }
        s  += __shfl_xor(s, 1);  s  += __shfl_xor(s, 2);
        s2 += __shfl_xor(s2, 1); s2 += __shfl_xor(s2, 2);
        r0 += __shfl_xor(r0, 1); r0 += __shfl_xor(r0, 2);
        r1 += __shfl_xor(r1, 1); r1 += __shfl_xor(r1, 2);
        r2 += __shfl_xor(r2, 1); r2 += __shfl_xor(r2, 2);
        if (part < 3) {
            float rv = part == 0 ? r0 : (part == 1 ? r1 : r2);
            featrgb[((size_t)bm * 3 + part) * HW + p_glob] = rv;
        }
        const float mu = s * 0.015625f;
        const float var = s2 * 0.015625f - mu * mu;
        const float rs = rsqrtf(var + 1e-6f);
        unsigned xw[8];
        #pragma unroll
        for (int j2 = 0; j2 < 8; ++j2) {
            const int ch = part * 16 + 2 * j2;
            float4 g0 = *(const float4*)&WL[ch * 8 + 4];
            float4 g1 = *(const float4*)&WL[ch * 8 + 12];
            xw[j2] = pk2((f[2 * j2] - mu) * rs * g0.x + g0.y,
                         (f[2 * j2 + 1] - mu) * rs * g1.x + g1.y);
        }
        *(uint4*)&XS[px_l * 72 + part * 16]     = make_uint4(xw[0], xw[1], xw[2], xw[3]);
        *(uint4*)&XS[px_l * 72 + part * 16 + 8] = make_uint4(xw[4], xw[5], xw[6], xw[7]);
    }

    // ---- B-fragments packed from f32 w_qkv via float4 loads ----
    bf16x8 Bf[3][2];
    #pragma unroll
    for (int jj = 0; jj < 3; ++jj) {
        int jt = wv + jj * 4;
        #pragma unroll
        for (int kc = 0; kc < 2; ++kc) {
            const float4* src = (const float4*)&w_qkv[(jt * 16 + col) * 64 + kc * 32 + grp * 8];
            float4 a = src[0], b = src[1];
            union { bf16x8 v; unsigned u[4]; } tmp;
            tmp.u[0] = pk2(a.x, a.y); tmp.u[1] = pk2(a.z, a.w);
            tmp.u[2] = pk2(b.x, b.y); tmp.u[3] = pk2(b.z, b.w);
            Bf[jj][kc] = tmp.v;
        }
    }
    __syncthreads();

    // ---- MFMA projection into TL buffers ----
    #pragma unroll
    for (int pt = 0; pt < 4; ++pt) {
        bf16x8 A0 = *(const bf16x8*)&XS[(pt * 16 + col) * 72 + grp * 8];
        bf16x8 A1 = *(const bf16x8*)&XS[(pt * 16 + col) * 72 + 32 + grp * 8];

        f32x4 aK = {0.f, 0.f, 0.f, 0.f};
        aK = __builtin_amdgcn_mfma_f32_16x16x32_bf16(Bf[1][0], A0, aK, 0, 0, 0);
        aK = __builtin_amdgcn_mfma_f32_16x16x32_bf16(Bf[1][1], A1, aK, 0, 0, 0);
        uint2 kw = {pk2(aK[0], aK[1]), pk2(aK[2], aK[3])};
        *(uint2*)&TLk[(pt * 16 + col) * 72 + wv * 16 + grp * 4] = kw;

        f32x4 aV = {0.f, 0.f, 0.f, 0.f};
        aV = __builtin_amdgcn_mfma_f32_16x16x32_bf16(A0, Bf[2][0], aV, 0, 0, 0);
        aV = __builtin_amdgcn_mfma_f32_16x16x32_bf16(A1, Bf[2][1], aV, 0, 0, 0);
        #pragma unroll
        for (int i = 0; i < 4; ++i)
            TLv[(pt * 16 + grp * 4 + i) * 72 + wv * 16 + col] = f2b(aV[i]);

        if (bm == 2) {
            f32x4 aQ = {0.f, 0.f, 0.f, 0.f};
            aQ = __builtin_amdgcn_mfma_f32_16x16x32_bf16(Bf[0][0], A0, aQ, 0, 0, 0);
            aQ = __builtin_amdgcn_mfma_f32_16x16x32_bf16(Bf[0][1], A1, aQ, 0, 0, 0);
            int p = p0 + pt * 16 + col;
            int qq = ((p >> 7) & 7) * 8 + (p & 7);
            float4 pq = *(const float4*)&pos_q[qq * 64 + wv * 16 + grp * 4];
            uint2 qw = {pk2((aQ[0] + pq.x) * PRE, (aQ[1] + pq.y) * PRE),
                        pk2((aQ[2] + pq.z) * PRE, (aQ[3] + pq.w) * PRE)};
            *(uint2*)&TLq[(pt * 16 + col) * 72 + wv * 16 + grp * 4] = qw;
        }
    }
    __syncthreads();

    // ---- coalesced copy-out ----
    #pragma unroll
    for (int it = 0; it < 2; ++it) {
        int j = it * 256 + tid;
        int row = j >> 3, seg = j & 7;
        *(uint4*)&kbuf[((size_t)pixbase + row) * 64 + seg * 8] =
            *(const uint4*)&TLk[row * 72 + seg * 8];
        *(uint4*)&vbuf[((size_t)pixbase + row) * 64 + seg * 8] =
            *(const uint4*)&TLv[row * 72 + seg * 8];
        if (bm == 2)
            *(uint4*)&qmid[((size_t)p0 + row) * 64 + seg * 8] =
                *(const uint4*)&TLq[row * 72 + seg * 8];
    }

    // ---- block 0 tail: wcomb = w_rgb @ w_out via LDS-staged w_out ----
    if (blk == 0) {
        float* WOL = (float*)TLk;
        __syncthreads();
        for (int i = tid; i < 4096; i += 256) WOL[i] = w_out[i];
        __syncthreads();
        for (int i = tid; i < 1024; i += 256) {
            short wc = 0;
            if (i < 192) {
                int c = i >> 6, e = i & 63;
                float a = 0.f;
                #pragma unroll 8
                for (int e2 = 0; e2 < 64; ++e2)
                    a = fmaf(WRL[c * 64 + e2], WOL[e2 * 64 + e], a);
                wc = f2b(a);
            }
            wcombb[i] = wc;
        }
    }
}

// ---------------------------------------------------------------------------
// Kernel 2: windowed attention + fused epilogue. 512 threads, wave = head.
// WAVE-PRIVATE staging: wave h stages only its own K column-slice
// (Klds[*][h*8..h*8+8)) and its own Vt rows (h*8..h*8+8) — the only data it
// reads. Same-wave DS ordering (proven by the P slot buffer) makes this
// barrier-free: the two pre-loop __syncthreads are GONE; only the epilogue
// barrier (cross-wave OL reads) remains. No straggler coupling.
// ---------------------------------------------------------------------------
__global__ __launch_bounds__(512, 6) void k_attn(
    const short* __restrict__ qmid, const short* __restrict__ kbuf,
    const short* __restrict__ vbuf,
    const float* __restrict__ pos_k, const float* __restrict__ b_rgb,
    const float* __restrict__ featrgb, const short* __restrict__ wcombb,
    float* __restrict__ outp)
{
    __shared__ char smem[48448];
    short* Klds = (short*)smem;                  // [144][72] bf16, K + pos_k
    short* Vt   = (short*)(smem + 20736);        // [64][152] bf16 + slack row 64
    short* OL   = (short*)smem;                  // overlay (head-column-sliced)
    // P slot buffers: smem + 40224, 1 KB per wave (8 waves)

    const int tid = threadIdx.x, blk = blockIdx.x;
    const int bm = blk >> 8, widx = blk & 255;
    const int wi = widx >> 4, wj = widx & 15;
    const int head = tid >> 6, lane = tid & 63;
    const int col = lane & 15, grp = lane >> 4;

    // ---- Q fragments first (independent loads, pos_q & scale pre-folded) ----
    uint4 qraw[4] = {{0,0,0,0},{0,0,0,0},{0,0,0,0},{0,0,0,0}};
    if (grp == 0) {
        #pragma unroll
        for (int qt = 0; qt < 4; ++qt) {
            int q = qt * 16 + col;
            int pix = (wi * 8 + (q >> 3)) * W_IMG + wj * 8 + (q & 7);
            qraw[qt] = *(const uint4*)&qmid[(size_t)pix * 64 + head * 8];
        }
    }

    // ---- wave-private staging: wave h covers keys lane, lane+64, lane+128 ----
    #pragma unroll
    for (int i = 0; i < 3; ++i) {
        const int kk = lane + i * 64;
        if (i == 2 && lane >= 16) continue;      // kk < 144
        const int r = kk / 12, c = kk - r * 12;
        const int hh = wi * 8 - 2 + r, ww = wj * 8 - 2 + c;
        uint4 kraw = {0, 0, 0, 0}, vraw = {0, 0, 0, 0};
        if ((unsigned)hh < 128u && (unsigned)ww < 128u) {
            size_t off = ((size_t)bm * HW + hh * W_IMG + ww) * 64 + head * 8;
            kraw = *(const uint4*)&kbuf[off];
            vraw = *(const uint4*)&vbuf[off];
        }
        const float* pk = &pos_k[kk * 64 + head * 8];
        float4 pk0 = *(const float4*)pk;
        float4 pk1 = *(const float4*)(pk + 4);
        union { uint4 q; short s[8]; } ku, vu;
        ku.q = kraw; vu.q = vraw;
        uint4 ko;
        ko.x = pk2(b2f(ku.s[0]) + pk0.x, b2f(ku.s[1]) + pk0.y);
        ko.y = pk2(b2f(ku.s[2]) + pk0.z, b2f(ku.s[3]) + pk0.w);
        ko.z = pk2(b2f(ku.s[4]) + pk1.x, b2f(ku.s[5]) + pk1.y);
        ko.w = pk2(b2f(ku.s[6]) + pk1.z, b2f(ku.s[7]) + pk1.w);
        *(uint4*)&Klds[kk * 72 + head * 8] = ko;
        #pragma unroll
        for (int cc = 0; cc < 8; ++cc)
            Vt[(head * 8 + cc) * 152 + kk] = vu.s[cc];
    }
    // zero this wave's Vt pad cols [144,152); wave 7 zeroes slack row 64 cols 0-7
    if (lane < 8) *(uint4*)&Vt[(head * 8 + lane) * 152 + 144] = (uint4){0, 0, 0, 0};
    if (head == 7 && lane == 0) *(uint4*)&Vt[64 * 152] = (uint4){0, 0, 0, 0};

    unsigned* PBh = (unsigned*)(smem + 40224 + head * 1024);
    const int slot_w = (grp * 16 + (col ^ grp)) * 4;
    const int g0 = 2 * (grp & 1);
    const int slotr1 = (g0 * 16 + (col ^ g0)) * 4 + (grp >> 1) * 2;
    const int slotr2 = ((g0 + 1) * 16 + (col ^ (g0 + 1))) * 4 + (grp >> 1) * 2;

    f32x4 oacc[4];
    float linv[4];

    #pragma unroll
    for (int qt = 0; qt < 4; ++qt) {
        union { bf16x8 v; uint4 r; } qu; qu.r = qraw[qt];
        const bf16x8 qf = qu.v;

        // ---- softmax, no max-subtract: p = exp2(s) directly ----
        float l = 0.f;
        unsigned pw[20];
        __builtin_amdgcn_s_setprio(1);
        #pragma unroll
        for (int t = 0; t < 9; ++t) {
            bf16x8 kf = *(const bf16x8*)&Klds[(t * 16 + col) * 72 + head * 8];
            f32x4 sct = __builtin_amdgcn_mfma_f32_16x16x32_bf16(
                kf, qf, (f32x4){0.f, 0.f, 0.f, 0.f}, 0, 0, 0);
            float e0 = fexp2(sct[0]), e1 = fexp2(sct[1]);
            float e2 = fexp2(sct[2]), e3 = fexp2(sct[3]);
            l += (e0 + e1) + (e2 + e3);
            pw[2 * t]     = pk2(e0, e1);
            pw[2 * t + 1] = pk2(e2, e3);
        }
        __builtin_amdgcn_s_setprio(0);
        pw[18] = 0u; pw[19] = 0u;
        l += __shfl_xor(l, 16);
        l += __shfl_xor(l, 32);
        linv[qt] = __builtin_amdgcn_rcpf(l);

        // ---- PV: O^T = V^T . P^T, P via slot-buffer exchange ----
        *(uint4*)(PBh + slot_w) = make_uint4(pw[0], pw[1], pw[2], pw[3]);
        f32x4 oa = {0.f, 0.f, 0.f, 0.f};
        __builtin_amdgcn_s_setprio(1);
        #pragma unroll
        for (int kt2 = 0; kt2 < 5; ++kt2) {
            uint2 r1 = *(const uint2*)(PBh + slotr1);
            uint2 r2 = *(const uint2*)(PBh + slotr2);
            if (kt2 < 4)
                *(uint4*)(PBh + slot_w) =
                    make_uint4(pw[4 * kt2 + 4], pw[4 * kt2 + 5], pw[4 * kt2 + 6], pw[4 * kt2 + 7]);
            union { bf16x8 v; unsigned u[4]; } pf;
            pf.u[0] = r1.x; pf.u[1] = r1.y; pf.u[2] = r2.x; pf.u[3] = r2.y;
            bf16x8 vf = *(const bf16x8*)&Vt[(head * 8 + (lane & 7)) * 152 + kt2 * 32 + grp * 8];
            oa = __builtin_amdgcn_mfma_f32_16x16x32_bf16(vf, pf.v, oa, 0, 0, 0);
        }
        __builtin_amdgcn_s_setprio(0);
        oacc[qt] = oa;
    }

    // ---- OL write: overlays THIS wave's own Klds column slice (in-order) ----
    if (grp < 2) {
        #pragma unroll
        for (int qt = 0; qt < 4; ++qt) {
            float s = linv[qt];
            uint2 ow;
            ow.x = pk2(oacc[qt][0] * s, oacc[qt][1] * s);
            ow.y = pk2(oacc[qt][2] * s, oacc[qt][3] * s);
            *(uint2*)&OL[(qt * 16 + col) * 72 + head * 8 + grp * 4] = ow;
        }
    }
    __syncthreads();   // the ONLY barrier: epilogue reads OL across heads

    // ---- fused epilogue: rgb = O@wcomb^T + featrgb + b_rgb (waves 0-3) ----
    if (head < 4) {
        const int qt = head;
        f32x4 acc = {0.f, 0.f, 0.f, 0.f};
        #pragma unroll
        for (int kc = 0; kc < 2; ++kc) {
            bf16x8 ao = *(const bf16x8*)&OL[(qt * 16 + col) * 72 + kc * 32 + grp * 8];
            bf16x8 bo = *(const bf16x8*)&wcombb[col * 64 + kc * 32 + grp * 8];
            acc = __builtin_amdgcn_mfma_f32_16x16x32_bf16(ao, bo, acc, 0, 0, 0);
        }
        if (col < 3) {
            float br = b_rgb[col];
            const float* frp = featrgb + ((size_t)bm * 3 + col) * HW;
            #pragma unroll
            for (int i = 0; i < 4; ++i) {
                int qs = qt * 16 + grp * 4 + i;
                int pix = (wi * 8 + (qs >> 3)) * W_IMG + wj * 8 + (qs & 7);
                outp[(size_t)bm * 3 * HW + col * HW + pix] = acc[i] + frp[pix] + br;
            }
        }
    }
}

// ---------------------------------------------------------------------------
extern "C" void kernel_launch(void* const* d_in, const int* in_sizes, int n_in,
                              void* d_out, int out_size, void* d_ws, size_t ws_size,
                              hipStream_t stream) {
    const float* x      = (const float*)d_in[0];
    const float* w_high = (const float*)d_in[1];
    const float* b_high = (const float*)d_in[2];
    const float* gamma  = (const float*)d_in[3];
    const float* beta   = (const float*)d_in[4];
    const float* w_qkv  = (const float*)d_in[5];
    const float* pos_q  = (const float*)d_in[6];
    const float* pos_k  = (const float*)d_in[7];
    const float* w_out  = (const float*)d_in[8];
    const float* w_rgb  = (const float*)d_in[9];
    const float* b_rgb  = (const float*)d_in[10];
    float* out = (float*)d_out;

    float* featrgb = (float*)d_ws;                         // [5][3][HW] f32
    short* kbuf    = (short*)(featrgb + (size_t)BM_TOT * 3 * HW);
    short* vbuf    = kbuf + (size_t)BM_TOT * HW * 64;
    short* qmid    = vbuf + (size_t)BM_TOT * HW * 64;      // [HW][64]
    short* wcombb  = qmid + (size_t)HW * 64;               // [16][64]

    k_qkv<<<BM_TOT * 256, 256, 0, stream>>>(x, w_qkv, w_high, b_high, gamma, beta,
                                            pos_q, w_rgb, w_out,
                                            featrgb, qmid, kbuf, vbuf, wcombb);
    k_attn<<<BM_TOT * 256, 512, 0, stream>>>(qmid, kbuf, vbuf, pos_k,
                                             b_rgb, featrgb, wcombb, out);
}